// Round 3
// baseline (2153.254 us; speedup 1.0000x reference)
//
#include <hip/hip_runtime.h>
#include <math.h>

#define NN 3136      // H*W = 56*56
#define CC 96
#define BB 8
#define KNB 9
#define PARTS 7      // m-range split for knn (7 m-tiles of 64 each)
#define FLT_MAX_ 3.402823466e+38f

// ---------------------------------------------------------------------------
// 1x1 conv as batched GEMM: out[b,o,n] = bias[o] + sum_k w[o*K+k] * in[b,k,n]
// Ping-pong LDS double buffer: ONE barrier per 16-wide K-chunk, global
// prefetch of chunk k+1 overlapped with compute on chunk k.
// ---------------------------------------------------------------------------
__global__ __launch_bounds__(256) void conv1_kernel(
    const float* __restrict__ in, const float* __restrict__ w,
    const float* __restrict__ bias, float* __restrict__ out, int K, int O)
{
    __shared__ float sW[2][16][64];   // [buf][kk][o]
    __shared__ float sX[2][16][64];   // [buf][kk][n]
    const int b  = blockIdx.z;
    const int n0 = blockIdx.x * 64;
    const int o0 = blockIdx.y * 64;
    const int tid = threadIdx.x;
    const int tx = tid & 15, ty = tid >> 4;
    const float* inb = in + (size_t)b * K * NN;

    // per-thread staging coordinates (constant)
    const int wo  = tid >> 2;            // 0..63  (output index within tile)
    const int wk4 = (tid & 3) << 2;      // 0,4,8,12
    const int xkk = tid >> 4;            // 0..15
    const int xn4 = (tid & 15) << 2;     // 0,4,...,60

    float acc[4][4] = {{0.f}};

    // preload chunk 0 into registers
    float4 wv = make_float4(0.f, 0.f, 0.f, 0.f);
    if (o0 + wo < O)
        wv = *(const float4*)&w[(size_t)(o0 + wo) * K + wk4];
    float4 xv = *(const float4*)&inb[(size_t)xkk * NN + n0 + xn4];

    // store chunk 0 into buffer 0
    sW[0][wk4 + 0][wo] = wv.x; sW[0][wk4 + 1][wo] = wv.y;
    sW[0][wk4 + 2][wo] = wv.z; sW[0][wk4 + 3][wo] = wv.w;
    *(float4*)&sX[0][xkk][xn4] = xv;

    int p = 0;
    for (int kb = 0; kb < K; kb += 16) {
        const bool has_next = (kb + 16) < K;
        float4 nwv = make_float4(0.f, 0.f, 0.f, 0.f);
        float4 nxv = make_float4(0.f, 0.f, 0.f, 0.f);
        if (has_next) {
            if (o0 + wo < O)
                nwv = *(const float4*)&w[(size_t)(o0 + wo) * K + kb + 16 + wk4];
            nxv = *(const float4*)&inb[(size_t)(kb + 16 + xkk) * NN + n0 + xn4];
        }
        __syncthreads();   // buffer p fully staged by all threads
        #pragma unroll
        for (int kk = 0; kk < 16; kk++) {
            const float4 av = *(const float4*)&sW[p][kk][ty << 2];
            const float4 xvv = *(const float4*)&sX[p][kk][tx << 2];
            float a_[4] = {av.x, av.y, av.z, av.w};
            float x_[4] = {xvv.x, xvv.y, xvv.z, xvv.w};
            #pragma unroll
            for (int i = 0; i < 4; i++)
                #pragma unroll
                for (int j = 0; j < 4; j++)
                    acc[i][j] = fmaf(a_[i], x_[j], acc[i][j]);
        }
        if (has_next) {
            const int q = p ^ 1;
            sW[q][wk4 + 0][wo] = nwv.x; sW[q][wk4 + 1][wo] = nwv.y;
            sW[q][wk4 + 2][wo] = nwv.z; sW[q][wk4 + 3][wo] = nwv.w;
            *(float4*)&sX[q][xkk][xn4] = nxv;
            p = q;
        }
    }
    #pragma unroll
    for (int i = 0; i < 4; i++) {
        int o = o0 + (ty << 2) + i;
        if (o < O) {
            float bo = bias[o];
            float4 v = make_float4(acc[i][0] + bo, acc[i][1] + bo,
                                   acc[i][2] + bo, acc[i][3] + bo);
            *(float4*)&out[((size_t)b * O + o) * NN + n0 + (tx << 2)] = v;
        }
    }
}

// ---------------------------------------------------------------------------
// Instance norm over N per (b,c) row; act: 0 none, 1 gelu, 2 relu
// ---------------------------------------------------------------------------
__global__ __launch_bounds__(256) void inorm_kernel(
    const float* __restrict__ in, float* __restrict__ out,
    const float* __restrict__ res, int act)
{
    const int row = blockIdx.x;
    const float* x = in + (size_t)row * NN;
    const int tid = threadIdx.x;

    float v[13];
    float s = 0.f;
    #pragma unroll
    for (int i = 0; i < 13; i++) {
        int idx = tid + i * 256;
        v[i] = (idx < NN) ? x[idx] : 0.f;
        s += v[i];
    }
    __shared__ float red[4];
    #pragma unroll
    for (int off = 32; off > 0; off >>= 1) s += __shfl_down(s, off);
    if ((tid & 63) == 0) red[tid >> 6] = s;
    __syncthreads();
    const float mean = (red[0] + red[1] + red[2] + red[3]) * (1.f / (float)NN);

    float s2 = 0.f;
    #pragma unroll
    for (int i = 0; i < 13; i++) {
        int idx = tid + i * 256;
        if (idx < NN) { float d = v[i] - mean; s2 = fmaf(d, d, s2); }
    }
    #pragma unroll
    for (int off = 32; off > 0; off >>= 1) s2 += __shfl_down(s2, off);
    __syncthreads();
    if ((tid & 63) == 0) red[tid >> 6] = s2;
    __syncthreads();
    const float var = (red[0] + red[1] + red[2] + red[3]) * (1.f / (float)NN);
    const float rs = rsqrtf(var + 1e-5f);

    float* o = out + (size_t)row * NN;
    const float* rr = res ? (res + (size_t)row * NN) : nullptr;
    #pragma unroll
    for (int i = 0; i < 13; i++) {
        int idx = tid + i * 256;
        if (idx < NN) {
            float y = (v[i] - mean) * rs;
            if (act == 1)      y = 0.5f * y * (1.f + erff(y * 0.70710678118654752f));
            else if (act == 2) y = fmaxf(y, 0.f);
            if (rr) y += rr[idx];
            o[idx] = y;
        }
    }
}

// ---------------------------------------------------------------------------
// Column (channel) L2-normalize + sq[b,n] = sum_c xn^2
// ---------------------------------------------------------------------------
__global__ __launch_bounds__(256) void colnorm_kernel(
    const float* __restrict__ xf, float* __restrict__ xn,
    float* __restrict__ sqc)
{
    const int g = blockIdx.x * 256 + threadIdx.x;   // over B*N
    const int b = g / NN;
    const int n = g - b * NN;
    const float* p = xf + (size_t)b * CC * NN + n;
    float* q = xn + (size_t)b * CC * NN + n;

    float s = 0.f;
    for (int c = 0; c < CC; c++) { float t = p[(size_t)c * NN]; s = fmaf(t, t, s); }
    const float den = fmaxf(sqrtf(s), 1e-12f);

    float sq = 0.f;
    for (int c = 0; c < CC; c++) {
        float t = p[(size_t)c * NN] / den;
        q[(size_t)c * NN] = t;
        sq = fmaf(t, t, sq);
    }
    sqc[g] = sq;
}

// ---------------------------------------------------------------------------
// top-9 register insertion helpers (fully unrolled -> stays in VGPRs)
// ---------------------------------------------------------------------------
__device__ __forceinline__ void ins9(float (&dv)[9], int (&di)[9], float d, int m)
{
    if (d < dv[8]) {
        dv[8] = d; di[8] = m;
        #pragma unroll
        for (int j = 8; j > 0; --j) {
            if (dv[j] < dv[j - 1]) {
                float tv = dv[j]; dv[j] = dv[j - 1]; dv[j - 1] = tv;
                int   ti = di[j]; di[j] = di[j - 1]; di[j - 1] = ti;
            }
        }
    }
}
__device__ __forceinline__ void ins9tb(float (&dv)[9], int (&di)[9], float d, int m)
{
    if (d < dv[8] || (d == dv[8] && m < di[8])) {
        dv[8] = d; di[8] = m;
        #pragma unroll
        for (int j = 8; j > 0; --j) {
            bool sw = (dv[j] < dv[j - 1]) ||
                      (dv[j] == dv[j - 1] && di[j] < di[j - 1]);
            if (sw) {
                float tv = dv[j]; dv[j] = dv[j - 1]; dv[j - 1] = tv;
                int   ti = di[j]; di[j] = di[j - 1]; di[j - 1] = ti;
            }
        }
    }
}

// ---------------------------------------------------------------------------
// kNN stage 1: per (b, 64-row tile, m-part) compute distances and per-row
// top-9 within the part. 256 threads, 2x8 micro-tile (2 lists/thread).
// d[m] = sq[m] - 2*dot(xn[:,r], xn[:,m]) + rp[r,m]   (sq[r] dropped)
// Partials out: pv/pi [(b*NN + r)*PARTS + part][9]
// ---------------------------------------------------------------------------
__global__ __launch_bounds__(256, 2) void knn_kernel(
    const float* __restrict__ xn, const float* __restrict__ sqc,
    const float* __restrict__ rp, float* __restrict__ pv, int* __restrict__ pi)
{
    __shared__ float shR[CC * 64];    // [c][r]   24 KB, persistent
    __shared__ float shC[48 * 64];    // [c][m]   12 KB, chunked over c
    const int b    = blockIdx.z;
    const int part = blockIdx.y;
    const int r0   = blockIdx.x * 64;
    const int tid  = threadIdx.x;
    const int tx = tid & 7;           // 8 col groups of 8
    const int ty = tid >> 3;          // 32 row groups of 2
    const float* xb = xn + (size_t)b * CC * NN;

    // stage 64-row slab of xn (float4, coalesced)
    #pragma unroll
    for (int i = 0; i < 6; i++) {
        int idx = tid + i * 256;              // < 1536 float4s
        int c = idx >> 4, r4 = (idx & 15) << 2;
        *(float4*)&shR[c * 64 + r4] = *(const float4*)&xb[(size_t)c * NN + r0 + r4];
    }

    float dv0[9], dv1[9]; int di0[9], di1[9];
    #pragma unroll
    for (int j = 0; j < 9; j++) { dv0[j] = dv1[j] = FLT_MAX_; di0[j] = di1[j] = 0x7fffffff; }

    const int rA = r0 + ty * 2;

    for (int mt = 0; mt < PARTS; mt++) {
        const int m0 = (part * PARTS + mt) * 64;
        float acc0[8] = {0.f, 0.f, 0.f, 0.f, 0.f, 0.f, 0.f, 0.f};
        float acc1[8] = {0.f, 0.f, 0.f, 0.f, 0.f, 0.f, 0.f, 0.f};

        for (int cb = 0; cb < CC; cb += 48) {
            __syncthreads();
            #pragma unroll
            for (int i = 0; i < 3; i++) {
                int idx = tid + i * 256;          // < 768 float4s
                int c = idx >> 4, m4 = (idx & 15) << 2;
                *(float4*)&shC[c * 64 + m4] =
                    *(const float4*)&xb[(size_t)(cb + c) * NN + m0 + m4];
            }
            __syncthreads();
            #pragma unroll 4
            for (int c = 0; c < 48; c++) {
                const float2 rv = *(const float2*)&shR[(cb + c) * 64 + ty * 2];
                const float4 c0 = *(const float4*)&shC[c * 64 + tx * 8];
                const float4 c1 = *(const float4*)&shC[c * 64 + tx * 8 + 4];
                acc0[0] = fmaf(rv.x, c0.x, acc0[0]);
                acc0[1] = fmaf(rv.x, c0.y, acc0[1]);
                acc0[2] = fmaf(rv.x, c0.z, acc0[2]);
                acc0[3] = fmaf(rv.x, c0.w, acc0[3]);
                acc0[4] = fmaf(rv.x, c1.x, acc0[4]);
                acc0[5] = fmaf(rv.x, c1.y, acc0[5]);
                acc0[6] = fmaf(rv.x, c1.z, acc0[6]);
                acc0[7] = fmaf(rv.x, c1.w, acc0[7]);
                acc1[0] = fmaf(rv.y, c0.x, acc1[0]);
                acc1[1] = fmaf(rv.y, c0.y, acc1[1]);
                acc1[2] = fmaf(rv.y, c0.z, acc1[2]);
                acc1[3] = fmaf(rv.y, c0.w, acc1[3]);
                acc1[4] = fmaf(rv.y, c1.x, acc1[4]);
                acc1[5] = fmaf(rv.y, c1.y, acc1[5]);
                acc1[6] = fmaf(rv.y, c1.z, acc1[6]);
                acc1[7] = fmaf(rv.y, c1.w, acc1[7]);
            }
        }

        // epilogue: distances + top-9 insertion
        const float4 s0 = *(const float4*)&sqc[(size_t)b * NN + m0 + tx * 8];
        const float4 s1 = *(const float4*)&sqc[(size_t)b * NN + m0 + tx * 8 + 4];
        const float4 a0 = *(const float4*)&rp[(size_t)rA * NN + m0 + tx * 8];
        const float4 a1 = *(const float4*)&rp[(size_t)rA * NN + m0 + tx * 8 + 4];
        const float4 b0 = *(const float4*)&rp[(size_t)(rA + 1) * NN + m0 + tx * 8];
        const float4 b1 = *(const float4*)&rp[(size_t)(rA + 1) * NN + m0 + tx * 8 + 4];
        const float sq_[8] = {s0.x, s0.y, s0.z, s0.w, s1.x, s1.y, s1.z, s1.w};
        const float rA_[8] = {a0.x, a0.y, a0.z, a0.w, a1.x, a1.y, a1.z, a1.w};
        const float rB_[8] = {b0.x, b0.y, b0.z, b0.w, b1.x, b1.y, b1.z, b1.w};
        #pragma unroll
        for (int j = 0; j < 8; j++) {
            const int m = m0 + tx * 8 + j;
            ins9(dv0, di0, fmaf(-2.f, acc0[j], sq_[j] + rA_[j]), m);
            ins9(dv1, di1, fmaf(-2.f, acc1[j], sq_[j] + rB_[j]), m);
        }
    }

    // merge the 8 tx-lists per row through LDS; 2 passes (row 0/1 of thread)
    float* mv = shR;             // 2304 floats needed, have 6144
    int*   mi = (int*)shC;       // 2304 ints needed, have 3072
    #pragma unroll
    for (int i = 0; i < 2; i++) {
        __syncthreads();
        #pragma unroll
        for (int j = 0; j < 9; j++) {
            mv[tid * 9 + j] = i ? dv1[j] : dv0[j];
            mi[tid * 9 + j] = i ? di1[j] : di0[j];
        }
        __syncthreads();
        if (tid < 32) {
            float bv[9]; int bi[9];
            #pragma unroll
            for (int j = 0; j < 9; j++) { bv[j] = FLT_MAX_; bi[j] = 0x7fffffff; }
            for (int t = 0; t < 8; t++) {
                const int base = (tid * 8 + t) * 9;
                #pragma unroll
                for (int j = 0; j < 9; j++)
                    ins9tb(bv, bi, mv[base + j], mi[base + j]);
            }
            const int r = r0 + tid * 2 + i;
            const size_t o = ((size_t)(b * NN + r) * PARTS + part) * KNB;
            #pragma unroll
            for (int j = 0; j < 9; j++) { pv[o + j] = bv[j]; pi[o + j] = bi[j]; }
        }
    }
}

// ---------------------------------------------------------------------------
// kNN stage 2: merge PARTS partial lists per (b,n) -> final nn_idx
// ---------------------------------------------------------------------------
__global__ __launch_bounds__(256) void knn_merge_kernel(
    const float* __restrict__ pv, const int* __restrict__ pi,
    int* __restrict__ nn_idx)
{
    const int g = blockIdx.x * 256 + threadIdx.x;   // over B*N
    if (g >= BB * NN) return;
    float bv[9]; int bi[9];
    #pragma unroll
    for (int j = 0; j < 9; j++) { bv[j] = FLT_MAX_; bi[j] = 0x7fffffff; }
    const float* v = pv + (size_t)g * PARTS * KNB;
    const int*   w = pi + (size_t)g * PARTS * KNB;
    for (int p = 0; p < PARTS; p++)
        #pragma unroll
        for (int j = 0; j < 9; j++)
            ins9tb(bv, bi, v[p * KNB + j], w[p * KNB + j]);
    #pragma unroll
    for (int j = 0; j < 9; j++) nn_idx[(size_t)g * KNB + j] = bi[j];
}

// ---------------------------------------------------------------------------
// Max-relative gather + channel interleave
// ---------------------------------------------------------------------------
__global__ __launch_bounds__(256) void gather_kernel(
    const float* __restrict__ xf, const int* __restrict__ nn_idx,
    float* __restrict__ y)
{
    const size_t g = (size_t)blockIdx.x * 256 + threadIdx.x;   // over B*C*N
    const int n  = (int)(g % NN);
    const int bc = (int)(g / NN);
    const int c  = bc % CC;
    const int b  = bc / CC;
    const float* row = xf + (size_t)(b * CC + c) * NN;
    const float xi = row[n];
    const int* id = nn_idx + ((size_t)b * NN + n) * KNB;
    float mx = -FLT_MAX_;
    #pragma unroll
    for (int k = 0; k < KNB; k++) mx = fmaxf(mx, row[id[k]] - xi);
    float* o = y + ((size_t)b * 2 * CC + 2 * c) * NN + n;
    o[0]  = xi;
    o[NN] = mx;
}

// ---------------------------------------------------------------------------
// Host-side orchestration
// ---------------------------------------------------------------------------
static void conv1(const float* in, const float* w, const float* b, float* out,
                  int K, int O, hipStream_t s)
{
    dim3 grid(NN / 64, (O + 63) / 64, BB);
    conv1_kernel<<<grid, 256, 0, s>>>(in, w, b, out, K, O);
}
static void inorm(const float* in, float* out, const float* res, int ch, int act,
                  hipStream_t s)
{
    inorm_kernel<<<BB * ch, 256, 0, s>>>(in, out, res, act);
}

struct GrapherP {
    const float *fc1w, *fc1b, *mrw, *mrb, *fc2w, *fc2b;
};

static void run_grapher(const float* in, const float* rp, const GrapherP& p,
                        float* outCur, float* bufA, float* bufB, float* xnb,
                        float* sqc, int* idx, hipStream_t s)
{
    conv1(in, p.fc1w, p.fc1b, bufA, CC, CC, s);
    inorm(bufA, bufB, nullptr, CC, 0, s);                         // xf
    colnorm_kernel<<<(BB * NN) / 256, 256, 0, s>>>(bufB, xnb, sqc);
    // partial-list scratch lives in bufA (free until gather writes it)
    float* pv = bufA;
    int*   pi = (int*)(bufA + (size_t)BB * NN * PARTS * KNB);
    knn_kernel<<<dim3(NN / 64, PARTS, BB), 256, 0, s>>>(xnb, sqc, rp, pv, pi);
    knn_merge_kernel<<<(BB * NN + 255) / 256, 256, 0, s>>>(pv, pi, idx);
    gather_kernel<<<(BB * CC * NN) / 256, 256, 0, s>>>(bufB, idx, bufA);  // 2C
    conv1(bufA, p.mrw, p.mrb, bufB, 2 * CC, 2 * CC, s);
    inorm(bufB, bufA, nullptr, 2 * CC, 1, s);                     // gelu
    conv1(bufA, p.fc2w, p.fc2b, bufB, 2 * CC, CC, s);
    inorm(bufB, outCur, in, CC, 0, s);                            // + shortcut
}

static void run_ffn(const float* in, const float* w1, const float* b1,
                    const float* w2, const float* b2,
                    float* outCur, float* bufA, float* bufB, hipStream_t s)
{
    conv1(in, w1, b1, bufA, CC, 4 * CC, s);
    inorm(bufA, bufB, nullptr, 4 * CC, 1, s);                     // gelu
    conv1(bufB, w2, b2, bufA, 2 * CC * 2, CC, s);
    inorm(bufA, outCur, in, CC, 0, s);                            // + shortcut
}

extern "C" void kernel_launch(void* const* d_in, const int* in_sizes, int n_in,
                              void* d_out, int out_size, void* d_ws, size_t ws_size,
                              hipStream_t stream)
{
    const float* x  = (const float*)d_in[0];
    const float* rp = (const float*)d_in[1];
    GrapherP g1 = {(const float*)d_in[2],  (const float*)d_in[3],
                   (const float*)d_in[4],  (const float*)d_in[5],
                   (const float*)d_in[6],  (const float*)d_in[7]};
    GrapherP g2 = {(const float*)d_in[8],  (const float*)d_in[9],
                   (const float*)d_in[10], (const float*)d_in[11],
                   (const float*)d_in[12], (const float*)d_in[13]};
    const float* f1w1 = (const float*)d_in[14]; const float* f1b1 = (const float*)d_in[15];
    const float* f1w2 = (const float*)d_in[16]; const float* f1b2 = (const float*)d_in[17];
    const float* f2w1 = (const float*)d_in[18]; const float* f2b1 = (const float*)d_in[19];
    const float* f2w2 = (const float*)d_in[20]; const float* f2b2 = (const float*)d_in[21];
    float* out = (float*)d_out;

    const size_t P  = (size_t)BB * CC * NN;     // 2,408,448 floats
    const size_t P4 = 4 * P;
    float* ws   = (float*)d_ws;
    float* bufA = ws;                 // P4
    float* bufB = bufA + P4;          // P4
    float* xnb  = bufB + P4;          // P
    float* cur0 = xnb + P;            // P
    float* cur1 = cur0 + P;           // P
    float* sqc  = cur1 + P;           // B*N
    int*   idx  = (int*)(sqc + (size_t)BB * NN);   // B*N*9 ints

    run_grapher(x, rp, g1, cur0, bufA, bufB, xnb, sqc, idx, stream);
    run_ffn(cur0, f1w1, f1b1, f1w2, f1b2, cur1, bufA, bufB, stream);
    inorm(cur1, cur0, nullptr, CC, 2, stream);
    run_grapher(cur0, rp, g2, cur1, bufA, bufB, xnb, sqc, idx, stream);
    run_ffn(cur1, f2w1, f2b1, f2w2, f2b2, cur0, bufA, bufB, stream);
    inorm(cur0, out, x, CC, 0, stream);
    (void)ws_size; (void)in_sizes; (void)n_in; (void)out_size;
}

// Round 4
// 1541.679 us; speedup vs baseline: 1.3967x; 1.3967x over previous
//
#include <hip/hip_runtime.h>
#include <math.h>

#define NN 3136      // H*W = 56*56
#define CC 96
#define BB 8
#define KNB 9
#define PARTS 7      // m-range split: 7 parts x 7 mt x 64 = 3136 cols
#define FLT_MAX_ 3.402823466e+38f

// ---------------------------------------------------------------------------
// 1x1 conv as batched GEMM (baseline version, known-good at 2051us session)
// ---------------------------------------------------------------------------
__global__ __launch_bounds__(256) void conv1_kernel(
    const float* __restrict__ in, const float* __restrict__ w,
    const float* __restrict__ bias, float* __restrict__ out, int K, int O)
{
    __shared__ float sW[16][64];   // [kk][o]
    __shared__ float sX[16][64];   // [kk][n]
    const int b  = blockIdx.z;
    const int n0 = blockIdx.x * 64;
    const int o0 = blockIdx.y * 64;
    const int tid = threadIdx.x;
    const int tx = tid & 15, ty = tid >> 4;
    const float* inb = in + (size_t)b * K * NN;

    float acc[4][4] = {{0.f}};

    for (int kb = 0; kb < K; kb += 16) {
        __syncthreads();
        {
            int o  = tid >> 2;
            int k4 = (tid & 3) << 2;
            float4 wv = make_float4(0.f, 0.f, 0.f, 0.f);
            if (o0 + o < O)
                wv = *(const float4*)&w[(size_t)(o0 + o) * K + kb + k4];
            sW[k4 + 0][o] = wv.x; sW[k4 + 1][o] = wv.y;
            sW[k4 + 2][o] = wv.z; sW[k4 + 3][o] = wv.w;
        }
        #pragma unroll
        for (int i = 0; i < 4; i++) {
            int e = tid + i * 256;
            int kk = e >> 6, n2 = e & 63;
            sX[kk][n2] = inb[(size_t)(kb + kk) * NN + n0 + n2];
        }
        __syncthreads();
        #pragma unroll
        for (int kk = 0; kk < 16; kk++) {
            const float4 av = *(const float4*)&sW[kk][ty << 2];
            const float4 xv = *(const float4*)&sX[kk][tx << 2];
            float a_[4] = {av.x, av.y, av.z, av.w};
            float x_[4] = {xv.x, xv.y, xv.z, xv.w};
            #pragma unroll
            for (int i = 0; i < 4; i++)
                #pragma unroll
                for (int j = 0; j < 4; j++)
                    acc[i][j] = fmaf(a_[i], x_[j], acc[i][j]);
        }
    }
    #pragma unroll
    for (int i = 0; i < 4; i++) {
        int o = o0 + (ty << 2) + i;
        if (o < O) {
            float bo = bias[o];
            float4 v = make_float4(acc[i][0] + bo, acc[i][1] + bo,
                                   acc[i][2] + bo, acc[i][3] + bo);
            *(float4*)&out[((size_t)b * O + o) * NN + n0 + (tx << 2)] = v;
        }
    }
}

// ---------------------------------------------------------------------------
// Instance norm over N per (b,c) row; act: 0 none, 1 gelu, 2 relu
// ---------------------------------------------------------------------------
__global__ __launch_bounds__(256) void inorm_kernel(
    const float* __restrict__ in, float* __restrict__ out,
    const float* __restrict__ res, int act)
{
    const int row = blockIdx.x;
    const float* x = in + (size_t)row * NN;
    const int tid = threadIdx.x;

    float v[13];
    float s = 0.f;
    #pragma unroll
    for (int i = 0; i < 13; i++) {
        int idx = tid + i * 256;
        v[i] = (idx < NN) ? x[idx] : 0.f;
        s += v[i];
    }
    __shared__ float red[4];
    #pragma unroll
    for (int off = 32; off > 0; off >>= 1) s += __shfl_down(s, off);
    if ((tid & 63) == 0) red[tid >> 6] = s;
    __syncthreads();
    const float mean = (red[0] + red[1] + red[2] + red[3]) * (1.f / (float)NN);

    float s2 = 0.f;
    #pragma unroll
    for (int i = 0; i < 13; i++) {
        int idx = tid + i * 256;
        if (idx < NN) { float d = v[i] - mean; s2 = fmaf(d, d, s2); }
    }
    #pragma unroll
    for (int off = 32; off > 0; off >>= 1) s2 += __shfl_down(s2, off);
    __syncthreads();
    if ((tid & 63) == 0) red[tid >> 6] = s2;
    __syncthreads();
    const float var = (red[0] + red[1] + red[2] + red[3]) * (1.f / (float)NN);
    const float rs = rsqrtf(var + 1e-5f);

    float* o = out + (size_t)row * NN;
    const float* rr = res ? (res + (size_t)row * NN) : nullptr;
    #pragma unroll
    for (int i = 0; i < 13; i++) {
        int idx = tid + i * 256;
        if (idx < NN) {
            float y = (v[i] - mean) * rs;
            if (act == 1)      y = 0.5f * y * (1.f + erff(y * 0.70710678118654752f));
            else if (act == 2) y = fmaxf(y, 0.f);
            if (rr) y += rr[idx];
            o[idx] = y;
        }
    }
}

// ---------------------------------------------------------------------------
// Column (channel) L2-normalize + sq[b,n] = sum_c xn^2
// ---------------------------------------------------------------------------
__global__ __launch_bounds__(256) void colnorm_kernel(
    const float* __restrict__ xf, float* __restrict__ xn,
    float* __restrict__ sqc)
{
    const int g = blockIdx.x * 256 + threadIdx.x;   // over B*N
    const int b = g / NN;
    const int n = g - b * NN;
    const float* p = xf + (size_t)b * CC * NN + n;
    float* q = xn + (size_t)b * CC * NN + n;

    float s = 0.f;
    for (int c = 0; c < CC; c++) { float t = p[(size_t)c * NN]; s = fmaf(t, t, s); }
    const float den = fmaxf(sqrtf(s), 1e-12f);

    float sq = 0.f;
    for (int c = 0; c < CC; c++) {
        float t = p[(size_t)c * NN] / den;
        q[(size_t)c * NN] = t;
        sq = fmaf(t, t, sq);
    }
    sqc[g] = sq;
}

// ---------------------------------------------------------------------------
// Distance GEMM: D[drow, m] = sq[m] - 2*dot(xn[:,r], xn[:,m]) + rp[r,m]
// (sq[r] dropped: constant per row, preserves top-k order and ties.)
// Pure GEMM -- no selection in this kernel. grid: (rowTiles, PARTS, nImages)
// ---------------------------------------------------------------------------
__global__ __launch_bounds__(256) void dist_gemm_kernel(
    const float* __restrict__ xn, const float* __restrict__ sqc,
    const float* __restrict__ rp, float* __restrict__ D,
    int row0, int b0)
{
    __shared__ float shR[CC * 64];    // [c][r]   24 KB
    __shared__ float shC[48 * 64];    // [c][m]   12 KB
    const int b    = b0 + blockIdx.z;
    const int part = blockIdx.y;
    const int rt   = blockIdx.x;
    const int r0g  = row0 + rt * 64;          // global row base
    const int tid  = threadIdx.x;
    const int tx = tid & 7;                   // 8 col groups of 8
    const int ty = tid >> 3;                  // 32 row groups of 2
    const float* xb  = xn  + (size_t)b * CC * NN;
    const float* sqb = sqc + (size_t)b * NN;

    // stage 64-row slab of xn (float4, coalesced)
    #pragma unroll
    for (int i = 0; i < 6; i++) {
        int idx = tid + i * 256;              // < 1536 float4s
        int c = idx >> 4, r4 = (idx & 15) << 2;
        *(float4*)&shR[c * 64 + r4] = *(const float4*)&xb[(size_t)c * NN + r0g + r4];
    }

    const int rAg = r0g + ty * 2;                               // global (rp)
    const size_t dA = (size_t)blockIdx.z * NN + rt * 64 + ty * 2; // local D row

    for (int mt = 0; mt < PARTS; mt++) {
        const int m0 = (part * PARTS + mt) * 64;
        float acc0[8] = {0.f, 0.f, 0.f, 0.f, 0.f, 0.f, 0.f, 0.f};
        float acc1[8] = {0.f, 0.f, 0.f, 0.f, 0.f, 0.f, 0.f, 0.f};

        for (int cb = 0; cb < CC; cb += 48) {
            __syncthreads();
            #pragma unroll
            for (int i = 0; i < 3; i++) {
                int idx = tid + i * 256;          // < 768 float4s
                int c = idx >> 4, m4 = (idx & 15) << 2;
                *(float4*)&shC[c * 64 + m4] =
                    *(const float4*)&xb[(size_t)(cb + c) * NN + m0 + m4];
            }
            __syncthreads();
            #pragma unroll 4
            for (int c = 0; c < 48; c++) {
                const float2 rv = *(const float2*)&shR[(cb + c) * 64 + ty * 2];
                const float4 c0 = *(const float4*)&shC[c * 64 + tx * 8];
                const float4 c1 = *(const float4*)&shC[c * 64 + tx * 8 + 4];
                acc0[0] = fmaf(rv.x, c0.x, acc0[0]);
                acc0[1] = fmaf(rv.x, c0.y, acc0[1]);
                acc0[2] = fmaf(rv.x, c0.z, acc0[2]);
                acc0[3] = fmaf(rv.x, c0.w, acc0[3]);
                acc0[4] = fmaf(rv.x, c1.x, acc0[4]);
                acc0[5] = fmaf(rv.x, c1.y, acc0[5]);
                acc0[6] = fmaf(rv.x, c1.z, acc0[6]);
                acc0[7] = fmaf(rv.x, c1.w, acc0[7]);
                acc1[0] = fmaf(rv.y, c0.x, acc1[0]);
                acc1[1] = fmaf(rv.y, c0.y, acc1[1]);
                acc1[2] = fmaf(rv.y, c0.z, acc1[2]);
                acc1[3] = fmaf(rv.y, c0.w, acc1[3]);
                acc1[4] = fmaf(rv.y, c1.x, acc1[4]);
                acc1[5] = fmaf(rv.y, c1.y, acc1[5]);
                acc1[6] = fmaf(rv.y, c1.z, acc1[6]);
                acc1[7] = fmaf(rv.y, c1.w, acc1[7]);
            }
        }

        // epilogue: distances -> D (no selection)
        const float4 s0 = *(const float4*)&sqb[m0 + tx * 8];
        const float4 s1 = *(const float4*)&sqb[m0 + tx * 8 + 4];
        const float4 a0 = *(const float4*)&rp[(size_t)rAg * NN + m0 + tx * 8];
        const float4 a1 = *(const float4*)&rp[(size_t)rAg * NN + m0 + tx * 8 + 4];
        const float4 b0v = *(const float4*)&rp[(size_t)(rAg + 1) * NN + m0 + tx * 8];
        const float4 b1v = *(const float4*)&rp[(size_t)(rAg + 1) * NN + m0 + tx * 8 + 4];
        float4 o00, o01, o10, o11;
        o00.x = fmaf(-2.f, acc0[0], s0.x + a0.x);
        o00.y = fmaf(-2.f, acc0[1], s0.y + a0.y);
        o00.z = fmaf(-2.f, acc0[2], s0.z + a0.z);
        o00.w = fmaf(-2.f, acc0[3], s0.w + a0.w);
        o01.x = fmaf(-2.f, acc0[4], s1.x + a1.x);
        o01.y = fmaf(-2.f, acc0[5], s1.y + a1.y);
        o01.z = fmaf(-2.f, acc0[6], s1.z + a1.z);
        o01.w = fmaf(-2.f, acc0[7], s1.w + a1.w);
        o10.x = fmaf(-2.f, acc1[0], s0.x + b0v.x);
        o10.y = fmaf(-2.f, acc1[1], s0.y + b0v.y);
        o10.z = fmaf(-2.f, acc1[2], s0.z + b0v.z);
        o10.w = fmaf(-2.f, acc1[3], s0.w + b0v.w);
        o11.x = fmaf(-2.f, acc1[4], s1.x + b1v.x);
        o11.y = fmaf(-2.f, acc1[5], s1.y + b1v.y);
        o11.z = fmaf(-2.f, acc1[6], s1.z + b1v.z);
        o11.w = fmaf(-2.f, acc1[7], s1.w + b1v.w);
        *(float4*)&D[dA * NN + m0 + tx * 8]           = o00;
        *(float4*)&D[dA * NN + m0 + tx * 8 + 4]       = o01;
        *(float4*)&D[(dA + 1) * NN + m0 + tx * 8]     = o10;
        *(float4*)&D[(dA + 1) * NN + m0 + tx * 8 + 4] = o11;
    }
}

// ---------------------------------------------------------------------------
// u64-key top-9 insertion: key = (ord(dist) << 32) | m.
// ord() maps float bits to unsigned order; min-u64 == (min dist, then min m)
// which reproduces the reference top_k tie-break (stable, lower index first).
// ---------------------------------------------------------------------------
__device__ __forceinline__ unsigned long long dkey(float d, int m)
{
    unsigned int ub = __float_as_uint(d);
    ub ^= (unsigned int)(((int)ub) >> 31) | 0x80000000u;
    return ((unsigned long long)ub << 32) | (unsigned int)m;
}
__device__ __forceinline__ void ins9u(unsigned long long (&kk)[9],
                                      unsigned long long key)
{
    if (key < kk[8]) {
        kk[8] = key;
        #pragma unroll
        for (int j = 8; j > 0; --j) {
            if (kk[j] < kk[j - 1]) {
                unsigned long long t = kk[j]; kk[j] = kk[j - 1]; kk[j - 1] = t;
            }
        }
    }
}

// ---------------------------------------------------------------------------
// kNN select: one wave per row of D. Lane-local sorted top-9 over ~49
// candidates, then a 9-round shfl tournament merge across the 64 lanes.
// grid.x = nrows/4, 256 threads (4 waves = 4 rows per block).
// ---------------------------------------------------------------------------
__global__ __launch_bounds__(256) void knn_select_kernel(
    const float* __restrict__ D, int* __restrict__ nn_out)
{
    const int r    = blockIdx.x * 4 + (threadIdx.x >> 6);
    const int lane = threadIdx.x & 63;
    const float* drow = D + (size_t)r * NN;

    unsigned long long kk[9];
    #pragma unroll
    for (int j = 0; j < 9; j++) kk[j] = 0xFFFFFFFFFFFFFFFFull;

    // 12 vectorized passes of 256 cols (float4/lane), then a 64-col tail
    #pragma unroll 2
    for (int jj = 0; jj < 12; jj++) {
        const int m0 = jj * 256 + lane * 4;
        const float4 v = *(const float4*)&drow[m0];
        ins9u(kk, dkey(v.x, m0 + 0));
        ins9u(kk, dkey(v.y, m0 + 1));
        ins9u(kk, dkey(v.z, m0 + 2));
        ins9u(kk, dkey(v.w, m0 + 3));
    }
    {
        const int m = 3072 + lane;
        ins9u(kk, dkey(drow[m], m));
    }

    // tournament: 9 rounds of wave-argmin over lane heads (kk[0])
    unsigned int my_out = 0;
    #pragma unroll
    for (int k = 0; k < 9; k++) {
        unsigned long long w = kk[0];
        #pragma unroll
        for (int off = 1; off < 64; off <<= 1) {
            unsigned int lo = (unsigned int)w;
            unsigned int hi = (unsigned int)(w >> 32);
            lo = __shfl_xor(lo, off);
            hi = __shfl_xor(hi, off);
            unsigned long long o = ((unsigned long long)hi << 32) | lo;
            w = (o < w) ? o : w;
        }
        if (kk[0] == w) {                // unique winner (keys contain m)
            #pragma unroll
            for (int j = 0; j < 8; j++) kk[j] = kk[j + 1];
            kk[8] = 0xFFFFFFFFFFFFFFFFull;
        }
        if (lane == k) my_out = (unsigned int)(w & 0xFFFFFFFFu);
    }
    if (lane < 9) nn_out[r * KNB + lane] = (int)my_out;
}

// ---------------------------------------------------------------------------
// Max-relative gather + channel interleave
// ---------------------------------------------------------------------------
__global__ __launch_bounds__(256) void gather_kernel(
    const float* __restrict__ xf, const int* __restrict__ nn_idx,
    float* __restrict__ y)
{
    const size_t g = (size_t)blockIdx.x * 256 + threadIdx.x;   // over B*C*N
    const int n  = (int)(g % NN);
    const int bc = (int)(g / NN);
    const int c  = bc % CC;
    const int b  = bc / CC;
    const float* row = xf + (size_t)(b * CC + c) * NN;
    const float xi = row[n];
    const int* id = nn_idx + ((size_t)b * NN + n) * KNB;
    float mx = -FLT_MAX_;
    #pragma unroll
    for (int k = 0; k < KNB; k++) mx = fmaxf(mx, row[id[k]] - xi);
    float* o = y + ((size_t)b * 2 * CC + 2 * c) * NN + n;
    o[0]  = xi;
    o[NN] = mx;
}

// ---------------------------------------------------------------------------
// Host-side orchestration
// ---------------------------------------------------------------------------
static void conv1(const float* in, const float* w, const float* b, float* out,
                  int K, int O, hipStream_t s)
{
    dim3 grid(NN / 64, (O + 63) / 64, BB);
    conv1_kernel<<<grid, 256, 0, s>>>(in, w, b, out, K, O);
}
static void inorm(const float* in, float* out, const float* res, int ch, int act,
                  hipStream_t s)
{
    inorm_kernel<<<BB * ch, 256, 0, s>>>(in, out, res, act);
}

struct GrapherP {
    const float *fc1w, *fc1b, *mrw, *mrb, *fc2w, *fc2b;
};

struct KnnWs {
    float* Dext;      // big-D region (may be null)
    int    ipc;       // images per chunk in big-D path (0 -> fallback)
    float* bufA;      // fallback row-chunked D (P4 floats, fits 1600*NN)
};

static void run_knn(const float* xnb, const float* sqc, const float* rp,
                    int* idx, const KnnWs& kw, hipStream_t s)
{
    if (kw.ipc >= 1) {
        for (int b0 = 0; b0 < BB; b0 += kw.ipc) {
            const int nb = (BB - b0 < kw.ipc) ? (BB - b0) : kw.ipc;
            dist_gemm_kernel<<<dim3(NN / 64, PARTS, nb), 256, 0, s>>>(
                xnb, sqc, rp, kw.Dext, 0, b0);
            knn_select_kernel<<<(nb * NN) / 4, 256, 0, s>>>(
                kw.Dext, idx + (size_t)b0 * NN * KNB);
        }
    } else {
        // row-chunked fallback inside bufA: chunks {1600, 1536} (mult of 64)
        for (int b = 0; b < BB; b++) {
            for (int row0 = 0; row0 < NN; ) {
                const int rows = (row0 == 0) ? 1600 : 1536;
                dist_gemm_kernel<<<dim3(rows / 64, PARTS, 1), 256, 0, s>>>(
                    xnb, sqc, rp, kw.bufA, row0, b);
                knn_select_kernel<<<rows / 4, 256, 0, s>>>(
                    kw.bufA, idx + ((size_t)b * NN + row0) * KNB);
                row0 += rows;
            }
        }
    }
}

static void run_grapher(const float* in, const float* rp, const GrapherP& p,
                        float* outCur, float* bufA, float* bufB, float* xnb,
                        float* sqc, int* idx, const KnnWs& kw, hipStream_t s)
{
    conv1(in, p.fc1w, p.fc1b, bufA, CC, CC, s);
    inorm(bufA, bufB, nullptr, CC, 0, s);                         // xf
    colnorm_kernel<<<(BB * NN) / 256, 256, 0, s>>>(bufB, xnb, sqc);
    run_knn(xnb, sqc, rp, idx, kw, s);
    gather_kernel<<<(BB * CC * NN) / 256, 256, 0, s>>>(bufB, idx, bufA);  // 2C
    conv1(bufA, p.mrw, p.mrb, bufB, 2 * CC, 2 * CC, s);
    inorm(bufB, bufA, nullptr, 2 * CC, 1, s);                     // gelu
    conv1(bufA, p.fc2w, p.fc2b, bufB, 2 * CC, CC, s);
    inorm(bufB, outCur, in, CC, 0, s);                            // + shortcut
}

static void run_ffn(const float* in, const float* w1, const float* b1,
                    const float* w2, const float* b2,
                    float* outCur, float* bufA, float* bufB, hipStream_t s)
{
    conv1(in, w1, b1, bufA, CC, 4 * CC, s);
    inorm(bufA, bufB, nullptr, 4 * CC, 1, s);                     // gelu
    conv1(bufB, w2, b2, bufA, 2 * CC * 2, CC, s);
    inorm(bufA, outCur, in, CC, 0, s);                            // + shortcut
}

extern "C" void kernel_launch(void* const* d_in, const int* in_sizes, int n_in,
                              void* d_out, int out_size, void* d_ws, size_t ws_size,
                              hipStream_t stream)
{
    const float* x  = (const float*)d_in[0];
    const float* rp = (const float*)d_in[1];
    GrapherP g1 = {(const float*)d_in[2],  (const float*)d_in[3],
                   (const float*)d_in[4],  (const float*)d_in[5],
                   (const float*)d_in[6],  (const float*)d_in[7]};
    GrapherP g2 = {(const float*)d_in[8],  (const float*)d_in[9],
                   (const float*)d_in[10], (const float*)d_in[11],
                   (const float*)d_in[12], (const float*)d_in[13]};
    const float* f1w1 = (const float*)d_in[14]; const float* f1b1 = (const float*)d_in[15];
    const float* f1w2 = (const float*)d_in[16]; const float* f1b2 = (const float*)d_in[17];
    const float* f2w1 = (const float*)d_in[18]; const float* f2b1 = (const float*)d_in[19];
    const float* f2w2 = (const float*)d_in[20]; const float* f2b2 = (const float*)d_in[21];
    float* out = (float*)d_out;

    const size_t P  = (size_t)BB * CC * NN;     // 2,408,448 floats
    const size_t P4 = 4 * P;
    float* ws   = (float*)d_ws;
    float* bufA = ws;                 // P4
    float* bufB = bufA + P4;          // P4
    float* xnb  = bufB + P4;          // P
    float* cur0 = xnb + P;            // P
    float* cur1 = cur0 + P;           // P
    float* sqc  = cur1 + P;           // B*N
    int*   idx  = (int*)(sqc + (size_t)BB * NN);   // B*N*9 ints
    float* wsend = (float*)(idx + (size_t)BB * NN * KNB);

    // size the distance-matrix scratch from the remaining workspace
    KnnWs kw;
    kw.bufA = bufA;
    const size_t used_f  = (size_t)(wsend - ws);
    const size_t total_f = ws_size / sizeof(float);
    const size_t avail_f = (total_f > used_f) ? (total_f - used_f) : 0;
    const size_t img_f   = (size_t)NN * NN;     // 9.83M floats per image
    kw.ipc  = (int)((avail_f >= img_f) ? ((avail_f / img_f < BB) ? avail_f / img_f : BB) : 0);
    kw.Dext = (kw.ipc >= 1) ? wsend : nullptr;

    run_grapher(x, rp, g1, cur0, bufA, bufB, xnb, sqc, idx, kw, stream);
    run_ffn(cur0, f1w1, f1b1, f1w2, f1b2, cur1, bufA, bufB, stream);
    inorm(cur1, cur0, nullptr, CC, 2, stream);
    run_grapher(cur0, rp, g2, cur1, bufA, bufB, xnb, sqc, idx, kw, stream);
    run_ffn(cur1, f2w1, f2b1, f2w2, f2b2, cur0, bufA, bufB, stream);
    inorm(cur0, out, x, CC, 0, stream);
    (void)in_sizes; (void)n_in; (void)out_size;
}

// Round 5
// 1300.223 us; speedup vs baseline: 1.6561x; 1.1857x over previous
//
#include <hip/hip_runtime.h>
#include <math.h>

#define NN 3136      // H*W = 56*56
#define CC 96
#define BB 8
#define KNB 9
#define PARTS 7      // m-range split: 7 parts x 7 mt x 64 = 3136 cols
#define FLT_MAX_ 3.402823466e+38f
typedef unsigned long long u64;

// ---------------------------------------------------------------------------
// 1x1 conv as batched GEMM (baseline version, known-good)
// ---------------------------------------------------------------------------
__global__ __launch_bounds__(256) void conv1_kernel(
    const float* __restrict__ in, const float* __restrict__ w,
    const float* __restrict__ bias, float* __restrict__ out, int K, int O)
{
    __shared__ float sW[16][64];   // [kk][o]
    __shared__ float sX[16][64];   // [kk][n]
    const int b  = blockIdx.z;
    const int n0 = blockIdx.x * 64;
    const int o0 = blockIdx.y * 64;
    const int tid = threadIdx.x;
    const int tx = tid & 15, ty = tid >> 4;
    const float* inb = in + (size_t)b * K * NN;

    float acc[4][4] = {{0.f}};

    for (int kb = 0; kb < K; kb += 16) {
        __syncthreads();
        {
            int o  = tid >> 2;
            int k4 = (tid & 3) << 2;
            float4 wv = make_float4(0.f, 0.f, 0.f, 0.f);
            if (o0 + o < O)
                wv = *(const float4*)&w[(size_t)(o0 + o) * K + kb + k4];
            sW[k4 + 0][o] = wv.x; sW[k4 + 1][o] = wv.y;
            sW[k4 + 2][o] = wv.z; sW[k4 + 3][o] = wv.w;
        }
        #pragma unroll
        for (int i = 0; i < 4; i++) {
            int e = tid + i * 256;
            int kk = e >> 6, n2 = e & 63;
            sX[kk][n2] = inb[(size_t)(kb + kk) * NN + n0 + n2];
        }
        __syncthreads();
        #pragma unroll
        for (int kk = 0; kk < 16; kk++) {
            const float4 av = *(const float4*)&sW[kk][ty << 2];
            const float4 xv = *(const float4*)&sX[kk][tx << 2];
            float a_[4] = {av.x, av.y, av.z, av.w};
            float x_[4] = {xv.x, xv.y, xv.z, xv.w};
            #pragma unroll
            for (int i = 0; i < 4; i++)
                #pragma unroll
                for (int j = 0; j < 4; j++)
                    acc[i][j] = fmaf(a_[i], x_[j], acc[i][j]);
        }
    }
    #pragma unroll
    for (int i = 0; i < 4; i++) {
        int o = o0 + (ty << 2) + i;
        if (o < O) {
            float bo = bias[o];
            float4 v = make_float4(acc[i][0] + bo, acc[i][1] + bo,
                                   acc[i][2] + bo, acc[i][3] + bo);
            *(float4*)&out[((size_t)b * O + o) * NN + n0 + (tx << 2)] = v;
        }
    }
}

// ---------------------------------------------------------------------------
// Instance norm over N per (b,c) row; act: 0 none, 1 gelu, 2 relu
// ---------------------------------------------------------------------------
__global__ __launch_bounds__(256) void inorm_kernel(
    const float* __restrict__ in, float* __restrict__ out,
    const float* __restrict__ res, int act)
{
    const int row = blockIdx.x;
    const float* x = in + (size_t)row * NN;
    const int tid = threadIdx.x;

    float v[13];
    float s = 0.f;
    #pragma unroll
    for (int i = 0; i < 13; i++) {
        int idx = tid + i * 256;
        v[i] = (idx < NN) ? x[idx] : 0.f;
        s += v[i];
    }
    __shared__ float red[4];
    #pragma unroll
    for (int off = 32; off > 0; off >>= 1) s += __shfl_down(s, off);
    if ((tid & 63) == 0) red[tid >> 6] = s;
    __syncthreads();
    const float mean = (red[0] + red[1] + red[2] + red[3]) * (1.f / (float)NN);

    float s2 = 0.f;
    #pragma unroll
    for (int i = 0; i < 13; i++) {
        int idx = tid + i * 256;
        if (idx < NN) { float d = v[i] - mean; s2 = fmaf(d, d, s2); }
    }
    #pragma unroll
    for (int off = 32; off > 0; off >>= 1) s2 += __shfl_down(s2, off);
    __syncthreads();
    if ((tid & 63) == 0) red[tid >> 6] = s2;
    __syncthreads();
    const float var = (red[0] + red[1] + red[2] + red[3]) * (1.f / (float)NN);
    const float rs = rsqrtf(var + 1e-5f);

    float* o = out + (size_t)row * NN;
    const float* rr = res ? (res + (size_t)row * NN) : nullptr;
    #pragma unroll
    for (int i = 0; i < 13; i++) {
        int idx = tid + i * 256;
        if (idx < NN) {
            float y = (v[i] - mean) * rs;
            if (act == 1)      y = 0.5f * y * (1.f + erff(y * 0.70710678118654752f));
            else if (act == 2) y = fmaxf(y, 0.f);
            if (rr) y += rr[idx];
            o[idx] = y;
        }
    }
}

// ---------------------------------------------------------------------------
// Column (channel) L2-normalize + sq[b,n] = sum_c xn^2
// ---------------------------------------------------------------------------
__global__ __launch_bounds__(256) void colnorm_kernel(
    const float* __restrict__ xf, float* __restrict__ xn,
    float* __restrict__ sqc)
{
    const int g = blockIdx.x * 256 + threadIdx.x;   // over B*N
    const int b = g / NN;
    const int n = g - b * NN;
    const float* p = xf + (size_t)b * CC * NN + n;
    float* q = xn + (size_t)b * CC * NN + n;

    float s = 0.f;
    for (int c = 0; c < CC; c++) { float t = p[(size_t)c * NN]; s = fmaf(t, t, s); }
    const float den = fmaxf(sqrtf(s), 1e-12f);

    float sq = 0.f;
    for (int c = 0; c < CC; c++) {
        float t = p[(size_t)c * NN] / den;
        q[(size_t)c * NN] = t;
        sq = fmaf(t, t, sq);
    }
    sqc[g] = sq;
}

// ---------------------------------------------------------------------------
// u64-key top-9: key = (ord(dist) << 32) | m.  min-u64 == (min d, then min m)
// == reference top_k tie-break (stable, lower index first).
// ---------------------------------------------------------------------------
__device__ __forceinline__ u64 dkey(float d, int m)
{
    unsigned int ub = __float_as_uint(d);
    ub ^= (unsigned int)(((int)ub) >> 31) | 0x80000000u;
    return ((u64)ub << 32) | (unsigned int)m;
}
__device__ __forceinline__ void ins9u(u64 (&kk)[9], u64 key)
{
    if (key < kk[8]) {
        kk[8] = key;
        #pragma unroll
        for (int j = 8; j > 0; --j) {
            if (kk[j] < kk[j - 1]) {
                u64 t = kk[j]; kk[j] = kk[j - 1]; kk[j - 1] = t;
            }
        }
    }
}

// ---------------------------------------------------------------------------
// Fused distance GEMM + top-9 select (v2).
// d[m] = sq[m] - 2*dot(xn[:,r], xn[:,m]) + rp[r,m]   (sq[r] dropped)
// Per-thread u64 top-9 over its 2x8 outputs across 7 m-tiles, then a
// 9-round shfl tournament across each aligned 8-lane row-group.
// Out: 9 sorted u64 keys per (row, part) -> pko.
// grid: (NN/64, PARTS, BB), 256 threads.
// ---------------------------------------------------------------------------
__global__ __launch_bounds__(256) void knn_fused_kernel(
    const float* __restrict__ xn, const float* __restrict__ sqc,
    const float* __restrict__ rp, u64* __restrict__ pko)
{
    __shared__ float shR[CC * 64];    // [c][r]   24 KB, persistent
    __shared__ float shC[CC * 64];    // [c][m]   24 KB, per m-tile (full 96 c)
    const int b    = blockIdx.z;
    const int part = blockIdx.y;
    const int r0   = blockIdx.x * 64;
    const int tid  = threadIdx.x;
    const int tx = tid & 7;           // 8 col groups of 8
    const int ty = tid >> 3;          // 32 row groups of 2
    const float* xb  = xn  + (size_t)b * CC * NN;
    const float* sqb = sqc + (size_t)b * NN;

    // stage 64-row slab of xn (float4, coalesced); covered by first barrier
    #pragma unroll
    for (int i = 0; i < 6; i++) {
        int idx = tid + i * 256;              // 1536 float4s
        int c = idx >> 4, r4 = (idx & 15) << 2;
        *(float4*)&shR[c * 64 + r4] = *(const float4*)&xb[(size_t)c * NN + r0 + r4];
    }

    u64 kk0[9], kk1[9];
    #pragma unroll
    for (int j = 0; j < 9; j++) { kk0[j] = kk1[j] = 0xFFFFFFFFFFFFFFFFull; }

    const int rA = r0 + ty * 2;

    for (int mt = 0; mt < PARTS; mt++) {
        const int m0 = (part * PARTS + mt) * 64;

        // issue rp/sq loads early (independent of LDS) -- latency hides
        // under the staging + 1536-FMA compute below.
        const float4 s0 = *(const float4*)&sqb[m0 + tx * 8];
        const float4 s1 = *(const float4*)&sqb[m0 + tx * 8 + 4];
        const float4 a0 = *(const float4*)&rp[(size_t)rA * NN + m0 + tx * 8];
        const float4 a1 = *(const float4*)&rp[(size_t)rA * NN + m0 + tx * 8 + 4];
        const float4 b0v = *(const float4*)&rp[(size_t)(rA + 1) * NN + m0 + tx * 8];
        const float4 b1v = *(const float4*)&rp[(size_t)(rA + 1) * NN + m0 + tx * 8 + 4];

        __syncthreads();   // prev mt's compute done before shC overwrite
        #pragma unroll
        for (int i = 0; i < 6; i++) {
            int idx = tid + i * 256;          // 1536 float4s (full 96 channels)
            int c = idx >> 4, m4 = (idx & 15) << 2;
            *(float4*)&shC[c * 64 + m4] =
                *(const float4*)&xb[(size_t)c * NN + m0 + m4];
        }
        __syncthreads();

        float acc0[8] = {0.f, 0.f, 0.f, 0.f, 0.f, 0.f, 0.f, 0.f};
        float acc1[8] = {0.f, 0.f, 0.f, 0.f, 0.f, 0.f, 0.f, 0.f};
        #pragma unroll 4
        for (int c = 0; c < CC; c++) {
            const float2 rv = *(const float2*)&shR[c * 64 + ty * 2];
            const float4 c0 = *(const float4*)&shC[c * 64 + tx * 8];
            const float4 c1 = *(const float4*)&shC[c * 64 + tx * 8 + 4];
            acc0[0] = fmaf(rv.x, c0.x, acc0[0]);
            acc0[1] = fmaf(rv.x, c0.y, acc0[1]);
            acc0[2] = fmaf(rv.x, c0.z, acc0[2]);
            acc0[3] = fmaf(rv.x, c0.w, acc0[3]);
            acc0[4] = fmaf(rv.x, c1.x, acc0[4]);
            acc0[5] = fmaf(rv.x, c1.y, acc0[5]);
            acc0[6] = fmaf(rv.x, c1.z, acc0[6]);
            acc0[7] = fmaf(rv.x, c1.w, acc0[7]);
            acc1[0] = fmaf(rv.y, c0.x, acc1[0]);
            acc1[1] = fmaf(rv.y, c0.y, acc1[1]);
            acc1[2] = fmaf(rv.y, c0.z, acc1[2]);
            acc1[3] = fmaf(rv.y, c0.w, acc1[3]);
            acc1[4] = fmaf(rv.y, c1.x, acc1[4]);
            acc1[5] = fmaf(rv.y, c1.y, acc1[5]);
            acc1[6] = fmaf(rv.y, c1.z, acc1[6]);
            acc1[7] = fmaf(rv.y, c1.w, acc1[7]);
        }

        // epilogue: distances -> u64 keys -> per-thread top-9
        const float sq_[8] = {s0.x, s0.y, s0.z, s0.w, s1.x, s1.y, s1.z, s1.w};
        const float rA_[8] = {a0.x, a0.y, a0.z, a0.w, a1.x, a1.y, a1.z, a1.w};
        const float rB_[8] = {b0v.x, b0v.y, b0v.z, b0v.w, b1v.x, b1v.y, b1v.z, b1v.w};
        #pragma unroll
        for (int j = 0; j < 8; j++) {
            const int m = m0 + tx * 8 + j;
            ins9u(kk0, dkey(fmaf(-2.f, acc0[j], sq_[j] + rA_[j]), m));
            ins9u(kk1, dkey(fmaf(-2.f, acc1[j], sq_[j] + rB_[j]), m));
        }
    }

    // tournament merge across the aligned 8-lane row-group (tx 0..7).
    // 9 rounds: butterfly-min of lane heads, pop the unique winner,
    // lane tx==0 stores the round winner (ascending order out).
    const size_t base0 = ((size_t)(b * NN + rA)     * PARTS + part) * KNB;
    const size_t base1 = ((size_t)(b * NN + rA + 1) * PARTS + part) * KNB;
    #pragma unroll
    for (int k = 0; k < 9; k++) {
        u64 w = kk0[0];
        #pragma unroll
        for (int off = 1; off < 8; off <<= 1) {
            unsigned int lo = __shfl_xor((unsigned int)w, off);
            unsigned int hi = __shfl_xor((unsigned int)(w >> 32), off);
            u64 o = ((u64)hi << 32) | lo;
            w = (o < w) ? o : w;
        }
        if (kk0[0] == w) {           // unique winner (keys contain m)
            #pragma unroll
            for (int j = 0; j < 8; j++) kk0[j] = kk0[j + 1];
            kk0[8] = 0xFFFFFFFFFFFFFFFFull;
        }
        if (tx == 0) pko[base0 + k] = w;
    }
    #pragma unroll
    for (int k = 0; k < 9; k++) {
        u64 w = kk1[0];
        #pragma unroll
        for (int off = 1; off < 8; off <<= 1) {
            unsigned int lo = __shfl_xor((unsigned int)w, off);
            unsigned int hi = __shfl_xor((unsigned int)(w >> 32), off);
            u64 o = ((u64)hi << 32) | lo;
            w = (o < w) ? o : w;
        }
        if (kk1[0] == w) {
            #pragma unroll
            for (int j = 0; j < 8; j++) kk1[j] = kk1[j + 1];
            kk1[8] = 0xFFFFFFFFFFFFFFFFull;
        }
        if (tx == 0) pko[base1 + k] = w;
    }
}

// ---------------------------------------------------------------------------
// Merge PARTS sorted 9-lists (u64 keys) per (b,n) -> final nn_idx
// ---------------------------------------------------------------------------
__global__ __launch_bounds__(256) void knn_merge_kernel(
    const u64* __restrict__ pko, int* __restrict__ nn_idx)
{
    const int g = blockIdx.x * 256 + threadIdx.x;   // over B*N
    if (g >= BB * NN) return;
    u64 kk[9];
    #pragma unroll
    for (int j = 0; j < 9; j++) kk[j] = 0xFFFFFFFFFFFFFFFFull;
    const u64* v = pko + (size_t)g * PARTS * KNB;
    for (int p = 0; p < PARTS; p++)
        #pragma unroll
        for (int j = 0; j < 9; j++)
            ins9u(kk, v[p * KNB + j]);
    #pragma unroll
    for (int j = 0; j < 9; j++)
        nn_idx[(size_t)g * KNB + j] = (int)(kk[j] & 0xFFFFFFFFu);
}

// ---------------------------------------------------------------------------
// Max-relative gather + channel interleave
// ---------------------------------------------------------------------------
__global__ __launch_bounds__(256) void gather_kernel(
    const float* __restrict__ xf, const int* __restrict__ nn_idx,
    float* __restrict__ y)
{
    const size_t g = (size_t)blockIdx.x * 256 + threadIdx.x;   // over B*C*N
    const int n  = (int)(g % NN);
    const int bc = (int)(g / NN);
    const int c  = bc % CC;
    const int b  = bc / CC;
    const float* row = xf + (size_t)(b * CC + c) * NN;
    const float xi = row[n];
    const int* id = nn_idx + ((size_t)b * NN + n) * KNB;
    float mx = -FLT_MAX_;
    #pragma unroll
    for (int k = 0; k < KNB; k++) mx = fmaxf(mx, row[id[k]] - xi);
    float* o = y + ((size_t)b * 2 * CC + 2 * c) * NN + n;
    o[0]  = xi;
    o[NN] = mx;
}

// ---------------------------------------------------------------------------
// Host-side orchestration
// ---------------------------------------------------------------------------
static void conv1(const float* in, const float* w, const float* b, float* out,
                  int K, int O, hipStream_t s)
{
    dim3 grid(NN / 64, (O + 63) / 64, BB);
    conv1_kernel<<<grid, 256, 0, s>>>(in, w, b, out, K, O);
}
static void inorm(const float* in, float* out, const float* res, int ch, int act,
                  hipStream_t s)
{
    inorm_kernel<<<BB * ch, 256, 0, s>>>(in, out, res, act);
}

struct GrapherP {
    const float *fc1w, *fc1b, *mrw, *mrb, *fc2w, *fc2b;
};

static void run_grapher(const float* in, const float* rp, const GrapherP& p,
                        float* outCur, float* bufA, float* bufB, float* xnb,
                        float* sqc, int* idx, hipStream_t s)
{
    conv1(in, p.fc1w, p.fc1b, bufA, CC, CC, s);
    inorm(bufA, bufB, nullptr, CC, 0, s);                         // xf
    colnorm_kernel<<<(BB * NN) / 256, 256, 0, s>>>(bufB, xnb, sqc);
    // partial-key scratch lives in bufA (free until gather writes it):
    // B*N*PARTS*9 u64 = 12.6 MB << P4 floats
    u64* pko = (u64*)bufA;
    knn_fused_kernel<<<dim3(NN / 64, PARTS, BB), 256, 0, s>>>(xnb, sqc, rp, pko);
    knn_merge_kernel<<<(BB * NN + 255) / 256, 256, 0, s>>>(pko, idx);
    gather_kernel<<<(BB * CC * NN) / 256, 256, 0, s>>>(bufB, idx, bufA);  // 2C
    conv1(bufA, p.mrw, p.mrb, bufB, 2 * CC, 2 * CC, s);
    inorm(bufB, bufA, nullptr, 2 * CC, 1, s);                     // gelu
    conv1(bufA, p.fc2w, p.fc2b, bufB, 2 * CC, CC, s);
    inorm(bufB, outCur, in, CC, 0, s);                            // + shortcut
}

static void run_ffn(const float* in, const float* w1, const float* b1,
                    const float* w2, const float* b2,
                    float* outCur, float* bufA, float* bufB, hipStream_t s)
{
    conv1(in, w1, b1, bufA, CC, 4 * CC, s);
    inorm(bufA, bufB, nullptr, 4 * CC, 1, s);                     // gelu
    conv1(bufB, w2, b2, bufA, 2 * CC * 2, CC, s);
    inorm(bufA, outCur, in, CC, 0, s);                            // + shortcut
}

extern "C" void kernel_launch(void* const* d_in, const int* in_sizes, int n_in,
                              void* d_out, int out_size, void* d_ws, size_t ws_size,
                              hipStream_t stream)
{
    const float* x  = (const float*)d_in[0];
    const float* rp = (const float*)d_in[1];
    GrapherP g1 = {(const float*)d_in[2],  (const float*)d_in[3],
                   (const float*)d_in[4],  (const float*)d_in[5],
                   (const float*)d_in[6],  (const float*)d_in[7]};
    GrapherP g2 = {(const float*)d_in[8],  (const float*)d_in[9],
                   (const float*)d_in[10], (const float*)d_in[11],
                   (const float*)d_in[12], (const float*)d_in[13]};
    const float* f1w1 = (const float*)d_in[14]; const float* f1b1 = (const float*)d_in[15];
    const float* f1w2 = (const float*)d_in[16]; const float* f1b2 = (const float*)d_in[17];
    const float* f2w1 = (const float*)d_in[18]; const float* f2b1 = (const float*)d_in[19];
    const float* f2w2 = (const float*)d_in[20]; const float* f2b2 = (const float*)d_in[21];
    float* out = (float*)d_out;

    const size_t P  = (size_t)BB * CC * NN;     // 2,408,448 floats
    const size_t P4 = 4 * P;
    float* ws   = (float*)d_ws;
    float* bufA = ws;                 // P4
    float* bufB = bufA + P4;          // P4
    float* xnb  = bufB + P4;          // P
    float* cur0 = xnb + P;            // P
    float* cur1 = cur0 + P;           // P
    float* sqc  = cur1 + P;           // B*N
    int*   idx  = (int*)(sqc + (size_t)BB * NN);   // B*N*9 ints

    run_grapher(x, rp, g1, cur0, bufA, bufB, xnb, sqc, idx, stream);
    run_ffn(cur0, f1w1, f1b1, f1w2, f1b2, cur1, bufA, bufB, stream);
    inorm(cur1, cur0, nullptr, CC, 2, stream);
    run_grapher(cur0, rp, g2, cur1, bufA, bufB, xnb, sqc, idx, stream);
    run_ffn(cur1, f2w1, f2b1, f2w2, f2b2, cur0, bufA, bufB, stream);
    inorm(cur0, out, x, CC, 0, stream);
    (void)in_sizes; (void)n_in; (void)out_size; (void)ws_size;
}